// Round 8
// baseline (213.576 us; speedup 1.0000x reference)
//
#include <hip/hip_runtime.h>

#define NROWS 4096
#define DIM   512
#define MARGIN 0.2f
#define EPS 1e-6f
#define BIG 1e9f
#define NBLOCKS 528             // 32*33/2 triangle tiles of 128x128
#define BPX 66                  // NBLOCKS / 8 (XCD swizzle)

typedef __attribute__((ext_vector_type(8))) short bf16x8;
typedef __attribute__((ext_vector_type(4))) float f32x4;

// monotone float <-> uint mapping (order-preserving), for atomicMax/Min on floats
__device__ __forceinline__ unsigned enc_f(float x) {
    unsigned u = __float_as_uint(x);
    return (u & 0x80000000u) ? ~u : (u | 0x80000000u);
}
__device__ __forceinline__ float dec_f(unsigned u) {
    return (u & 0x80000000u) ? __uint_as_float(u ^ 0x80000000u) : __uint_as_float(~u);
}

__device__ __forceinline__ unsigned short f2bf_rne(float x) {
    unsigned u = __float_as_uint(x);
    unsigned r = u + 0x7FFFu + ((u >> 16) & 1u);
    return (unsigned short)(r >> 16);
}

// split f32 feats into bf16 hi + lo; also init hp/hn and the done-counter
__global__ void prep_kernel(const float* __restrict__ feats,
                            unsigned short* __restrict__ fhi,
                            unsigned short* __restrict__ flo,
                            unsigned* __restrict__ hp,
                            unsigned* __restrict__ hn,
                            unsigned* __restrict__ counter) {
    const int gid = blockIdx.x * 256 + threadIdx.x;
    if (gid < NROWS) {
        hp[gid] = enc_f(-BIG);
        hn[gid] = enc_f(BIG);
    }
    if (gid == 0) *counter = 0u;
    const int i = gid * 4;
    const float4 v = *(const float4*)&feats[i];
    float x[4] = {v.x, v.y, v.z, v.w};
    unsigned short h[4], l[4];
#pragma unroll
    for (int j = 0; j < 4; j++) {
        h[j] = f2bf_rne(x[j]);
        const float hf = __uint_as_float(((unsigned)h[j]) << 16);
        l[j] = f2bf_rne(x[j] - hf);
    }
    *(ushort4*)&fhi[i] = make_ushort4(h[0], h[1], h[2], h[3]);
    *(ushort4*)&flo[i] = make_ushort4(l[0], l[1], l[2], l[3]);
}

// Fused bf16x3 Gram GEMM + batch-hard mining, lower-triangle 128x128 tiles.
// R8: NO LDS, NO BARRIERS. Fragments load straight from global (L2/L3-resident
// 8.4MB working set; each vector load = 16 rows x 64B = 16 fully-used cache
// lines). Register ping-pong double-buffer (named sets, static indexing);
// 48 MFMA between load clusters covers L2 latency via ILP; waves are fully
// independent so nothing ever drains. Fragment content and MFMA order are
// bit-identical to R3 (proven absmax 0.0).
__launch_bounds__(256, 2)
__global__ void gram_mine_kernel(const unsigned short* __restrict__ fhi,
                                 const unsigned short* __restrict__ flo,
                                 const int* __restrict__ labels,
                                 unsigned* __restrict__ hp,
                                 unsigned* __restrict__ hn,
                                 unsigned* __restrict__ counter,
                                 float* __restrict__ out) {
    __shared__ unsigned sold;

    const int tid = threadIdx.x;
    const int lane = tid & 63;
    const int w = tid >> 6;        // wave 0..3
    const int wm = w >> 1;         // wave row 0..1
    const int wn = w & 1;          // wave col 0..1

    // XCD-aware bijective swizzle (528 = 8*66), then triangle unrank (bx <= by)
    const int bid = blockIdx.x;
    const int t0 = (bid & 7) * BPX + (bid >> 3);
    int by = (int)((sqrtf(8.0f * (float)t0 + 1.0f) - 1.0f) * 0.5f);
    while ((by + 1) * (by + 2) / 2 <= t0) by++;
    while (by * (by + 1) / 2 > t0) by--;
    const int bx = t0 - by * (by + 1) / 2;
    const int r0 = by * 128;
    const int c0 = bx * 128;
    const bool offdiag = (by != bx);

    const int frow = lane & 15;     // fragment row/col within 16
    const int fkg = lane >> 4;      // k-group 0..3 (8 bf16 each)

    // per-lane fragment base pointers (A rows for this wave's wm, B rows for wn)
    const unsigned short* pAh = fhi + (size_t)(r0 + wm * 64 + frow) * DIM + fkg * 8;
    const unsigned short* pAl = flo + (size_t)(r0 + wm * 64 + frow) * DIM + fkg * 8;
    const unsigned short* pBh = fhi + (size_t)(c0 + wn * 64 + frow) * DIM + fkg * 8;
    const unsigned short* pBl = flo + (size_t)(c0 + wn * 64 + frow) * DIM + fkg * 8;

#define LOADF(AH, AL, BH, BL, kt)                                                       \
    {                                                                                   \
        _Pragma("unroll")                                                               \
        for (int mi = 0; mi < 4; mi++) {                                                \
            AH[mi] = *(const bf16x8*)(pAh + (size_t)mi * 16 * DIM + (kt) * 32);         \
            AL[mi] = *(const bf16x8*)(pAl + (size_t)mi * 16 * DIM + (kt) * 32);         \
        }                                                                               \
        _Pragma("unroll")                                                               \
        for (int nj = 0; nj < 4; nj++) {                                                \
            BH[nj] = *(const bf16x8*)(pBh + (size_t)nj * 16 * DIM + (kt) * 32);         \
            BL[nj] = *(const bf16x8*)(pBl + (size_t)nj * 16 * DIM + (kt) * 32);         \
        }                                                                               \
    }

#define MFMA3(AH, AL, BH, BL)                                                           \
    {                                                                                   \
        _Pragma("unroll")                                                               \
        for (int mi = 0; mi < 4; mi++)                                                  \
            _Pragma("unroll")                                                           \
            for (int nj = 0; nj < 4; nj++)                                              \
                acc[mi][nj] = __builtin_amdgcn_mfma_f32_16x16x32_bf16(AH[mi], BH[nj],   \
                                                                      acc[mi][nj], 0, 0, 0); \
        _Pragma("unroll")                                                               \
        for (int mi = 0; mi < 4; mi++)                                                  \
            _Pragma("unroll")                                                           \
            for (int nj = 0; nj < 4; nj++)                                              \
                acc[mi][nj] = __builtin_amdgcn_mfma_f32_16x16x32_bf16(AH[mi], BL[nj],   \
                                                                      acc[mi][nj], 0, 0, 0); \
        _Pragma("unroll")                                                               \
        for (int mi = 0; mi < 4; mi++)                                                  \
            _Pragma("unroll")                                                           \
            for (int nj = 0; nj < 4; nj++)                                              \
                acc[mi][nj] = __builtin_amdgcn_mfma_f32_16x16x32_bf16(AL[mi], BH[nj],   \
                                                                      acc[mi][nj], 0, 0, 0); \
    }

    f32x4 acc[4][4];
#pragma unroll
    for (int i = 0; i < 4; i++)
#pragma unroll
        for (int j = 0; j < 4; j++) acc[i][j] = (f32x4)(0.0f);

    bf16x8 cah[4], cal[4], cbh[4], cbl[4];   // current K-tile fragments
    bf16x8 nah[4], nal[4], nbh[4], nbl[4];   // next K-tile fragments

    LOADF(cah, cal, cbh, cbl, 0)

    for (int kt = 0; kt < 16; kt += 2) {
        LOADF(nah, nal, nbh, nbl, kt + 1)    // issue next loads, then MFMA current
        MFMA3(cah, cal, cbh, cbl)
        if (kt < 14) LOADF(cah, cal, cbh, cbl, kt + 2)
        MFMA3(nah, nal, nbh, nbl)
    }

    // ---- fused batch-hard mining (C frag: col = frow, row = fkg*4 + reg) ----
    int rlab[4][4], clab[4];
#pragma unroll
    for (int mi = 0; mi < 4; mi++)
#pragma unroll
        for (int rg = 0; rg < 4; rg++)
            rlab[mi][rg] = labels[r0 + wm * 64 + mi * 16 + fkg * 4 + rg];
#pragma unroll
    for (int nj = 0; nj < 4; nj++)
        clab[nj] = labels[c0 + wn * 64 + nj * 16 + frow];

    float pmax[4][4], nmin[4][4];   // row-anchor
    float cpmax[4], cnmin[4];       // col-anchor (symmetric pass)
#pragma unroll
    for (int mi = 0; mi < 4; mi++)
#pragma unroll
        for (int rg = 0; rg < 4; rg++) { pmax[mi][rg] = -BIG; nmin[mi][rg] = BIG; }
#pragma unroll
    for (int nj = 0; nj < 4; nj++) { cpmax[nj] = -BIG; cnmin[nj] = BIG; }

#pragma unroll
    for (int mi = 0; mi < 4; mi++)
#pragma unroll
        for (int nj = 0; nj < 4; nj++)
#pragma unroll
            for (int rg = 0; rg < 4; rg++) {
                const float dist = 1.0f - acc[mi][nj][rg];
                if (rlab[mi][rg] == clab[nj]) {
                    if (dist > EPS) {
                        pmax[mi][rg] = fmaxf(pmax[mi][rg], dist);
                        cpmax[nj] = fmaxf(cpmax[nj], dist);
                    }
                } else {
                    nmin[mi][rg] = fminf(nmin[mi][rg], dist);
                    cnmin[nj] = fminf(cnmin[nj], dist);
                }
            }

    // row-anchor reduce across 16 cols (lanes with same fkg)
#pragma unroll
    for (int off = 8; off; off >>= 1) {
#pragma unroll
        for (int mi = 0; mi < 4; mi++)
#pragma unroll
            for (int rg = 0; rg < 4; rg++) {
                pmax[mi][rg] = fmaxf(pmax[mi][rg], __shfl_xor(pmax[mi][rg], off, 16));
                nmin[mi][rg] = fminf(nmin[mi][rg], __shfl_xor(nmin[mi][rg], off, 16));
            }
    }
    if (frow == 0) {
#pragma unroll
        for (int mi = 0; mi < 4; mi++)
#pragma unroll
            for (int rg = 0; rg < 4; rg++) {
                const int R = r0 + wm * 64 + mi * 16 + fkg * 4 + rg;
                atomicMax(&hp[R], enc_f(pmax[mi][rg]));
                atomicMin(&hn[R], enc_f(nmin[mi][rg]));
            }
    }

    // col-anchor reduce across the 16 rows (xor 16, 32); skip on diagonal
    if (offdiag) {
#pragma unroll
        for (int nj = 0; nj < 4; nj++) {
            cpmax[nj] = fmaxf(cpmax[nj], __shfl_xor(cpmax[nj], 16, 64));
            cpmax[nj] = fmaxf(cpmax[nj], __shfl_xor(cpmax[nj], 32, 64));
            cnmin[nj] = fminf(cnmin[nj], __shfl_xor(cnmin[nj], 16, 64));
            cnmin[nj] = fminf(cnmin[nj], __shfl_xor(cnmin[nj], 32, 64));
        }
        if (fkg == 0) {
#pragma unroll
            for (int nj = 0; nj < 4; nj++) {
                const int C = c0 + wn * 64 + nj * 16 + frow;
                atomicMax(&hp[C], enc_f(cpmax[nj]));
                atomicMin(&hn[C], enc_f(cnmin[nj]));
            }
        }
    }

    // ---- last-block finalize (device-scope counter) ----
    __threadfence();
    __syncthreads();
    if (tid == 0) sold = atomicAdd(counter, 1u);
    __syncthreads();
    if (sold == NBLOCKS - 1 && tid < 64) {
        __threadfence();
        float sum = 0.0f;
        int cnt = 0;
        for (int i = tid; i < NROWS; i += 64) {
            const float p = dec_f(__hip_atomic_load(&hp[i], __ATOMIC_RELAXED, __HIP_MEMORY_SCOPE_AGENT));
            const float n = dec_f(__hip_atomic_load(&hn[i], __ATOMIC_RELAXED, __HIP_MEMORY_SCOPE_AGENT));
            const float tl = p - n + MARGIN;
            if (tl > 0.0f) { sum += tl; cnt++; }
        }
#pragma unroll
        for (int off = 32; off; off >>= 1) {
            sum += __shfl_down(sum, off, 64);
            cnt += __shfl_down(cnt, off, 64);
        }
        if (tid == 0) out[0] = (cnt > 0) ? sum / (float)cnt : 0.0f;
    }
#undef LOADF
#undef MFMA3
}

extern "C" void kernel_launch(void* const* d_in, const int* in_sizes, int n_in,
                              void* d_out, int out_size, void* d_ws, size_t ws_size,
                              hipStream_t stream) {
    const float* feats = (const float*)d_in[0];
    const int* labels = (const int*)d_in[1];
    float* out = (float*)d_out;

    unsigned* hp = (unsigned*)d_ws;                                   // 4096 u32
    unsigned* hn = hp + NROWS;                                        // 4096 u32
    unsigned* counter = hn + NROWS;                                   // 1 u32
    unsigned short* fhi = (unsigned short*)((char*)d_ws + 33024);     // 256B-aligned
    unsigned short* flo = fhi + (size_t)NROWS * DIM;

    prep_kernel<<<(NROWS * DIM) / (256 * 4), 256, 0, stream>>>(feats, fhi, flo, hp, hn, counter);
    gram_mine_kernel<<<NBLOCKS, 256, 0, stream>>>(fhi, flo, labels, hp, hn, counter, out);
}